// Round 6
// baseline (1065.182 us; speedup 1.0000x reference)
//
#include <hip/hip_runtime.h>
#include <hip/hip_bf16.h>
#include <math.h>

#define NTOK 8192     // B*T
#define DD   1024
#define HH   4096
#define NE   8
#define BM 256
#define BN 256
#define SLOT_CAP (2 * NTOK + NE * BM)   // 18432

typedef __bf16 bf16;
typedef __bf16 bf16x8 __attribute__((ext_vector_type(8)));
typedef __bf16 bf16x4 __attribute__((ext_vector_type(4)));
typedef float  f32x4  __attribute__((ext_vector_type(4)));

typedef __attribute__((address_space(3))) unsigned char lds_u8;
typedef const __attribute__((address_space(1))) unsigned char g_u8;

__device__ __forceinline__ void gload16(const bf16* g, bf16* l) {
  __builtin_amdgcn_global_load_lds((g_u8*)g, (lds_u8*)l, 16, 0, 0);
}

__device__ __forceinline__ float softplus_f(float v) {
  return fmaxf(v, 0.f) + log1pf(expf(-fabsf(v)));
}

// ---------------- K1: gating (1 wave per token) ----------------
__global__ __launch_bounds__(64) void moe_gate_kernel(
    const float* __restrict__ x, const float* __restrict__ noise,
    const float* __restrict__ gate_w, const float* __restrict__ gate_b,
    const float* __restrict__ var_w,  const float* __restrict__ var_b,
    float* __restrict__ coef2, int* __restrict__ t2e, int* __restrict__ counts)
{
  const int t = blockIdx.x;
  const int lane = threadIdx.x;
  const float* xt = x + (size_t)t * DD;
  float pg[NE], pv[NE];
  #pragma unroll
  for (int e = 0; e < NE; ++e) { pg[e] = 0.f; pv[e] = 0.f; }
  #pragma unroll 4
  for (int i = 0; i < DD / 64; ++i) {
    const int d = lane + i * 64;
    const float xv = xt[d];
    #pragma unroll
    for (int e = 0; e < NE; ++e) {
      pg[e] = fmaf(xv, gate_w[e * DD + d], pg[e]);
      pv[e] = fmaf(xv, var_w[e * DD + d], pv[e]);
    }
  }
  #pragma unroll
  for (int e = 0; e < NE; ++e) {
    #pragma unroll
    for (int off = 32; off; off >>= 1) {
      pg[e] += __shfl_xor(pg[e], off);
      pv[e] += __shfl_xor(pv[e], off);
    }
  }
  if (lane == 0) {
    float noisy[NE];
    #pragma unroll
    for (int e = 0; e < NE; ++e) {
      const float lg = pg[e] + gate_b[e];
      const float sd = softplus_f(pv[e] + var_b[e]);
      noisy[e] = lg + noise[t * NE + e] * sd;
    }
    int i1 = 0; float n1 = noisy[0];
    #pragma unroll
    for (int e = 1; e < NE; ++e) if (noisy[e] > n1) { n1 = noisy[e]; i1 = e; }
    int i2 = -1; float n2 = -3.0e38f;
    #pragma unroll
    for (int e = 0; e < NE; ++e) if (e != i1 && noisy[e] > n2) { n2 = noisy[e]; i2 = e; }
    const float e2 = expf(n2 - n1);
    const float den = 1.f + e2;
    coef2[t * 2 + 0] = 1.f / den;
    coef2[t * 2 + 1] = e2 / den;
    t2e[t * 2 + 0] = i1;
    t2e[t * 2 + 1] = i2;
    atomicAdd(&counts[i1], 1);
    atomicAdd(&counts[i2], 1);
  }
}

// ---------------- K2: padded segment offsets (pad to BM=256) ----------------
__global__ void moe_offsets_kernel(const int* __restrict__ counts, int* __restrict__ po) {
  if (threadIdx.x == 0) {
    int acc = 0;
    po[0] = 0;
    for (int e = 0; e < NE; ++e) {
      acc += ((counts[e] + BM - 1) / BM) * BM;
      po[e + 1] = acc;
    }
  }
}

// ---------------- K3: scatter tokens into padded slots ----------------
__global__ __launch_bounds__(256) void moe_scatter_kernel(
    const int* __restrict__ t2e, const float* __restrict__ coef2,
    const int* __restrict__ po, int* __restrict__ cnt2,
    int* __restrict__ assign_tok, float* __restrict__ slot_coef)
{
  const int t = blockIdx.x * 256 + threadIdx.x;
  if (t >= NTOK) return;
  #pragma unroll
  for (int k = 0; k < 2; ++k) {
    const int e = t2e[t * 2 + k];
    const int pos = atomicAdd(&cnt2[e], 1);
    const int slot = po[e] + pos;
    assign_tok[slot] = t;
    slot_coef[slot] = coef2[t * 2 + k];
  }
}

// ---------------- K4: f32 -> bf16 converter (grid-stride over float4) ----------------
__global__ __launch_bounds__(256) void cvt_bf16_kernel(const float* __restrict__ src,
                                                       bf16* __restrict__ dst, int n4) {
  for (int i = blockIdx.x * 256 + threadIdx.x; i < n4; i += gridDim.x * 256) {
    const float4 f = ((const float4*)src)[i];
    bf16x4 v;
    v[0] = (bf16)f.x; v[1] = (bf16)f.y; v[2] = (bf16)f.z; v[3] = (bf16)f.w;
    ((bf16x4*)dst)[i] = v;
  }
}

// ---------------- grouped GEMM: 256^2, 8 waves, 4-phase, issue-early staging ----------------
// LDS [2 buf][256 rows][64 cols] per operand, phys chunk16 = logical ^ (row&7)
// (round-2-verified: SQ_LDS_BANK_CONFLICT == 0).
// All 4 stage groups for tile kt+1 issue at phase 0 of tile kt (into the idle
// buffer; safe: prior tile's reads of that buffer ended before the last
// barrier). Single vmcnt(0) per K-tile at phase 0 — loads issued ~4 phases
// earlier, so the wait is mostly pre-drained. No counted vmcnt (every LDS
// region is consumed at phase 0 by some wave; partial publication is
// impossible with this wave->row map).
#define MFMA16(AR, BR, MB)                                                   \
  __builtin_amdgcn_s_setprio(1);                                             \
  _Pragma("unroll")                                                          \
  for (int m_ = 0; m_ < 4; ++m_)                                             \
    _Pragma("unroll")                                                        \
    for (int n_ = 0; n_ < 4; ++n_)                                           \
      acc[MB + m_][n_] = __builtin_amdgcn_mfma_f32_16x16x32_bf16(            \
          AR[m_], BR[n_], acc[MB + m_][n_], 0, 0, 0);                        \
  __builtin_amdgcn_s_setprio(0);

#define RD_A(DST, MOFF, SZ)                                                  \
  _Pragma("unroll")                                                          \
  for (int m_ = 0; m_ < 4; ++m_)                                             \
    DST[m_] = *(const bf16x8*)(Ab + aBase + (MOFF + m_) * 1024 + SZ);

#define RD_B(DST, SZ)                                                        \
  _Pragma("unroll")                                                          \
  for (int n_ = 0; n_ < 4; ++n_)                                             \
    DST[n_] = *(const bf16x8*)(Bb + bBase + n_ * 1024 + SZ);

#define VMCNT0 asm volatile("s_waitcnt vmcnt(0)" ::: "memory")
#define BAR    asm volatile("s_barrier" ::: "memory")

template<int KDIM, int KSTRIDE, int NCOLS, bool FFN1>
__global__ __launch_bounds__(512, 2) void moe_gemm_kernel(
    const bf16* __restrict__ Asrc, const bf16* __restrict__ Wsrc,
    const float* __restrict__ bias,
    const int* __restrict__ assign_tok, const float* __restrict__ slot_coef,
    const int* __restrict__ po,
    bf16* __restrict__ hout, float* __restrict__ out,
    int chunk_base, int gx)
{
  constexpr int NK = KDIM / 64;
  __shared__ bf16 smA[2 * BM * 64];   // 64 KB
  __shared__ bf16 smB[2 * BN * 64];   // 64 KB
  __shared__ int toks[BM];

  // bijective XCD chunk swizzle (m204)
  const int nwg = gridDim.x;
  const int lin = blockIdx.x;
  const int q = nwg >> 3, r = nwg & 7;
  const int xcd = lin & 7, idx = lin >> 3;
  const int wg = (xcd < r ? xcd * (q + 1) : r * (q + 1) + (xcd - r) * q) + idx;
  const int bx = wg % gx, by = wg / gx;

  const int row0 = chunk_base + bx * BM;
  const int po8 = po[NE];
  if (row0 >= po8) return;
  int e = 0;
  while (row0 >= po[e + 1]) ++e;
  const int bn0 = by * BN;
  const size_t kbase = (size_t)blockIdx.z * KDIM;
  const bf16* We = Wsrc + (size_t)e * ((size_t)HH * DD) + kbase;
  const bf16* As = Asrc + kbase;

  const int tid = threadIdx.x, lane = tid & 63, wid = tid >> 6;
  if (tid < BM) toks[tid] = assign_tok[row0 + tid];
  __syncthreads();   // full drain; publishes toks

  // staging pointers: thread t, half h, instr j -> row = h*128 + j*64 + (t>>3),
  // phys chunk = t&7, source logical chunk = (t&7) ^ (row&7)
  const int srcc = ((tid & 7) ^ ((tid >> 3) & 7)) * 8;
  const bf16* ap[2][2];
  const bf16* bp[2][2];
  #pragma unroll
  for (int h = 0; h < 2; ++h)
    #pragma unroll
    for (int j = 0; j < 2; ++j) {
      const int row = h * 128 + j * 64 + (tid >> 3);
      int ar;
      if constexpr (FFN1) {
        const int s = toks[row];
        ar = s < 0 ? 0 : s;
      } else {
        ar = row0 - chunk_base + row;
      }
      ap[h][j] = As + (size_t)ar * KSTRIDE + srcc;
      bp[h][j] = We + (size_t)(bn0 + row) * KSTRIDE + srcc;
    }

  auto stageAll = [&](int b, int kt) {
    const int ko = kt * 64;
    #pragma unroll
    for (int h = 0; h < 2; ++h)
      #pragma unroll
      for (int j = 0; j < 2; ++j)
        gload16(ap[h][j] + ko, &smA[b * 16384 + h * 8192 + (j * 512 + tid) * 8]);
    #pragma unroll
    for (int h = 0; h < 2; ++h)
      #pragma unroll
      for (int j = 0; j < 2; ++j)
        gload16(bp[h][j] + ko, &smB[b * 16384 + h * 8192 + (j * 512 + tid) * 8]);
  };

  const int wr = wid >> 2, wc = wid & 3;   // 2(M) x 4(N) wave grid
  const int la = lane & 15, hi = lane >> 4;
  const int aBase = (wr * 128 + la) * 64;  // + m*1024
  const int bBase = (wc * 64 + la) * 64;   // + n*1024
  const int sz0 = ((hi)     ^ (la & 7)) * 8;   // k-slot 0 chunk
  const int sz1 = ((4 + hi) ^ (la & 7)) * 8;   // k-slot 1 chunk

  f32x4 acc[8][4];
  #pragma unroll
  for (int m = 0; m < 8; ++m)
    #pragma unroll
    for (int n = 0; n < 4; ++n) acc[m][n] = {0.f, 0.f, 0.f, 0.f};

  // prologue: stage K-tile 0 into buffer 0
  stageAll(0, 0);

  bf16x8 aX[4], aY[4], bb0[4], bb1[4];
  for (int kt = 0; kt < NK; ++kt) {
    const int b = kt & 1, nb = b ^ 1;
    const bf16* Ab = smA + b * 16384;
    const bf16* Bb = smB + b * 16384;

    // ---- phase 0: publish tile kt; issue ALL stages for kt+1; MFMA k0 lo ----
    VMCNT0;                 // loads issued ~4 phases ago -> mostly drained
    BAR;
    RD_A(aX, 0, sz0);
    RD_B(bb0, sz0);
    RD_A(aY, 0, sz1);
    if (kt + 1 < NK) stageAll(nb, kt + 1);
    MFMA16(aX, bb0, 0);
    BAR;

    // ---- phase 1: MFMA k1 lo; pre-read A(m4-7,k1) ----
    BAR;
    RD_B(bb1, sz1);
    RD_A(aX, 4, sz1);
    MFMA16(aY, bb1, 0);
    BAR;

    // ---- phase 2: MFMA k1 hi; pre-read A(m4-7,k0) ----
    BAR;
    RD_A(aY, 4, sz0);
    MFMA16(aX, bb1, 4);
    BAR;

    // ---- phase 3: MFMA k0 hi ----
    BAR;
    MFMA16(aY, bb0, 4);
    BAR;
  }

  if constexpr (FFN1) {
    const int hrow0 = row0 - chunk_base;
    #pragma unroll
    for (int n = 0; n < 4; ++n) {
      const int col = bn0 + wc * 64 + n * 16 + la;
      const float bb = bias[e * NCOLS + col];
      #pragma unroll
      for (int m = 0; m < 8; ++m) {
        const int rl = wr * 128 + m * 16 + hi * 4;
        #pragma unroll
        for (int rr = 0; rr < 4; ++rr) {
          float v = acc[m][n][rr] + bb;
          v = v > 0.f ? v : 0.f;
          hout[(size_t)(hrow0 + rl + rr) * HH + col] = (bf16)v;
        }
      }
    }
  } else {
    const bool addb = (blockIdx.z == 0);
    #pragma unroll
    for (int n = 0; n < 4; ++n) {
      const int col = bn0 + wc * 64 + n * 16 + la;
      const float bb = addb ? bias[e * NCOLS + col] : 0.f;
      #pragma unroll
      for (int m = 0; m < 8; ++m) {
        const int rl = wr * 128 + m * 16 + hi * 4;
        #pragma unroll
        for (int rr = 0; rr < 4; ++rr) {
          const int tl = rl + rr;
          const int tok = toks[tl];
          if (tok >= 0) {
            const float c = slot_coef[row0 + tl];
            atomicAdd(out + (size_t)tok * DD + col, c * (acc[m][n][rr] + bb));
          }
        }
      }
    }
  }
}

extern "C" void kernel_launch(void* const* d_in, const int* in_sizes, int n_in,
                              void* d_out, int out_size, void* d_ws, size_t ws_size,
                              hipStream_t stream) {
  const float* x      = (const float*)d_in[0];
  const float* noise  = (const float*)d_in[1];
  const float* gate_w = (const float*)d_in[2];
  const float* gate_b = (const float*)d_in[3];
  const float* var_w  = (const float*)d_in[4];
  const float* var_b  = (const float*)d_in[5];
  const float* w1     = (const float*)d_in[6];
  const float* b1     = (const float*)d_in[7];
  const float* w2     = (const float*)d_in[8];
  const float* b2     = (const float*)d_in[9];
  float* out = (float*)d_out;
  (void)in_sizes; (void)n_in; (void)out_size;

  char* ws = (char*)d_ws;
  size_t off = 0;
  auto alloc = [&](size_t bytes) {
    off = (off + 255) & ~(size_t)255;
    size_t o = off;
    off += bytes;
    return o;
  };
  bf16*  xb         = (bf16*)(ws + alloc((size_t)NTOK * DD * 2));
  float* coef2      = (float*)(ws + alloc((size_t)NTOK * 2 * 4));
  int*   t2e        = (int*)(ws + alloc((size_t)NTOK * 2 * 4));
  int*   counts     = (int*)(ws + alloc(64));   // counts[8] + cnt2[8]
  int*   cnt2       = counts + 8;
  int*   po         = (int*)(ws + alloc(64));
  int*   assign_tok = (int*)(ws + alloc((size_t)SLOT_CAP * 4));
  float* slot_coef  = (float*)(ws + alloc((size_t)SLOT_CAP * 4));
  bf16*  w1b        = (bf16*)(ws + alloc((size_t)NE * HH * DD * 2));  // 64 MB
  bf16*  w2b        = (bf16*)(ws + alloc((size_t)NE * DD * HH * 2));  // 64 MB
  off = (off + 255) & ~(size_t)255;
  const size_t h_avail = ws_size > off ? ws_size - off : 0;
  int chunk_rows = (int)(h_avail / ((size_t)HH * 2));
  chunk_rows = (chunk_rows / BM) * BM;
  if (chunk_rows < BM) chunk_rows = BM;
  if (chunk_rows > SLOT_CAP) chunk_rows = SLOT_CAP;
  bf16* hbuf = (bf16*)(ws + off);

  hipMemsetAsync(counts, 0, 64, stream);
  hipMemsetAsync(assign_tok, 0xFF, (size_t)SLOT_CAP * 4, stream);  // -1
  hipMemsetAsync(out, 0, (size_t)NTOK * DD * 4, stream);

  moe_gate_kernel<<<NTOK, 64, 0, stream>>>(x, noise, gate_w, gate_b, var_w, var_b,
                                           coef2, t2e, counts);
  moe_offsets_kernel<<<1, 64, 0, stream>>>(counts, po);
  moe_scatter_kernel<<<NTOK / 256, 256, 0, stream>>>(t2e, coef2, po, cnt2,
                                                     assign_tok, slot_coef);
  cvt_bf16_kernel<<<2048, 256, 0, stream>>>(x, xb, NTOK * DD / 4);
  cvt_bf16_kernel<<<2048, 256, 0, stream>>>(w1, w1b, NE * HH * DD / 4);
  cvt_bf16_kernel<<<2048, 256, 0, stream>>>(w2, w2b, NE * DD * HH / 4);

  const int rounds = (SLOT_CAP + chunk_rows - 1) / chunk_rows;
  for (int r = 0; r < rounds; ++r) {
    const int cb = r * chunk_rows;
    const int rows_here = (cb + chunk_rows <= SLOT_CAP) ? chunk_rows : (SLOT_CAP - cb);
    const int gx = rows_here / BM;
    dim3 g1(gx * (HH / BN), 1, 1);
    moe_gemm_kernel<DD, DD, HH, true><<<g1, 512, 0, stream>>>(
        xb, w1b, b1, assign_tok, slot_coef, po, hbuf, nullptr, cb, gx);
    dim3 g2(gx * (DD / BN), 1, 4);   // K split x4: 1024 per split
    moe_gemm_kernel<HH / 4, HH, DD, false><<<g2, 512, 0, stream>>>(
        hbuf, w2b, b2, assign_tok, slot_coef, po, nullptr, out, cb, gx);
  }
}

// Round 7
// 956.634 us; speedup vs baseline: 1.1135x; 1.1135x over previous
//
#include <hip/hip_runtime.h>
#include <hip/hip_bf16.h>
#include <math.h>

#define NTOK 8192     // B*T
#define DD   1024
#define HH   4096
#define NE   8
#define BM 128
#define BN 128
#define BK 64
#define SLOT_CAP (2 * NTOK + NE * BM)   // 17408

typedef __bf16 bf16;
typedef __bf16 bf16x8 __attribute__((ext_vector_type(8)));
typedef __bf16 bf16x4 __attribute__((ext_vector_type(4)));
typedef float  f32x4  __attribute__((ext_vector_type(4)));

typedef __attribute__((address_space(3))) unsigned char lds_u8;
typedef const __attribute__((address_space(1))) unsigned char g_u8;

__device__ __forceinline__ void gload16(const bf16* g, bf16* l) {
  __builtin_amdgcn_global_load_lds((g_u8*)g, (lds_u8*)l, 16, 0, 0);
}

__device__ __forceinline__ float softplus_f(float v) {
  return fmaxf(v, 0.f) + log1pf(expf(-fabsf(v)));
}

// ---------------- K1: gating (1 wave per token) + x->bf16 fold ----------------
__global__ __launch_bounds__(64) void moe_gate_kernel(
    const float* __restrict__ x, const float* __restrict__ noise,
    const float* __restrict__ gate_w, const float* __restrict__ gate_b,
    const float* __restrict__ var_w,  const float* __restrict__ var_b,
    float* __restrict__ coef2, int* __restrict__ t2e, int* __restrict__ counts,
    bf16* __restrict__ xb)
{
  const int t = blockIdx.x;
  const int lane = threadIdx.x;
  const float* xt = x + (size_t)t * DD;
  bf16* xbt = xb + (size_t)t * DD;
  float pg[NE], pv[NE];
  #pragma unroll
  for (int e = 0; e < NE; ++e) { pg[e] = 0.f; pv[e] = 0.f; }
  #pragma unroll 4
  for (int i = 0; i < DD / 64; ++i) {
    const int d = lane + i * 64;
    const float xv = xt[d];
    xbt[d] = (bf16)xv;                    // folded x->bf16 conversion
    #pragma unroll
    for (int e = 0; e < NE; ++e) {
      pg[e] = fmaf(xv, gate_w[e * DD + d], pg[e]);
      pv[e] = fmaf(xv, var_w[e * DD + d], pv[e]);
    }
  }
  #pragma unroll
  for (int e = 0; e < NE; ++e) {
    #pragma unroll
    for (int off = 32; off; off >>= 1) {
      pg[e] += __shfl_xor(pg[e], off);
      pv[e] += __shfl_xor(pv[e], off);
    }
  }
  if (lane == 0) {
    float noisy[NE];
    #pragma unroll
    for (int e = 0; e < NE; ++e) {
      const float lg = pg[e] + gate_b[e];
      const float sd = softplus_f(pv[e] + var_b[e]);
      noisy[e] = lg + noise[t * NE + e] * sd;
    }
    int i1 = 0; float n1 = noisy[0];
    #pragma unroll
    for (int e = 1; e < NE; ++e) if (noisy[e] > n1) { n1 = noisy[e]; i1 = e; }
    int i2 = -1; float n2 = -3.0e38f;
    #pragma unroll
    for (int e = 0; e < NE; ++e) if (e != i1 && noisy[e] > n2) { n2 = noisy[e]; i2 = e; }
    const float e2 = expf(n2 - n1);
    const float den = 1.f + e2;
    coef2[t * 2 + 0] = 1.f / den;
    coef2[t * 2 + 1] = e2 / den;
    t2e[t * 2 + 0] = i1;
    t2e[t * 2 + 1] = i2;
    atomicAdd(&counts[i1], 1);
    atomicAdd(&counts[i2], 1);
  }
}

// ---------------- K2: padded segment offsets (pad to BM=128) ----------------
__global__ void moe_offsets_kernel(const int* __restrict__ counts, int* __restrict__ po) {
  if (threadIdx.x == 0) {
    int acc = 0;
    po[0] = 0;
    for (int e = 0; e < NE; ++e) {
      acc += ((counts[e] + BM - 1) / BM) * BM;
      po[e + 1] = acc;
    }
  }
}

// ---------------- K3: scatter tokens into padded slots ----------------
__global__ __launch_bounds__(256) void moe_scatter_kernel(
    const int* __restrict__ t2e, const float* __restrict__ coef2,
    const int* __restrict__ po, int* __restrict__ cnt2,
    int* __restrict__ assign_tok, float* __restrict__ slot_coef)
{
  const int t = blockIdx.x * 256 + threadIdx.x;
  if (t >= NTOK) return;
  #pragma unroll
  for (int k = 0; k < 2; ++k) {
    const int e = t2e[t * 2 + k];
    const int pos = atomicAdd(&cnt2[e], 1);
    const int slot = po[e] + pos;
    assign_tok[slot] = t;
    slot_coef[slot] = coef2[t * 2 + k];
  }
}

// ---------------- K4: f32 -> bf16 converter (grid-stride over float4) ----------------
__global__ __launch_bounds__(256) void cvt_bf16_kernel(const float* __restrict__ src,
                                                       bf16* __restrict__ dst, int n4) {
  for (int i = blockIdx.x * 256 + threadIdx.x; i < n4; i += gridDim.x * 256) {
    const float4 f = ((const float4*)src)[i];
    bf16x4 v;
    v[0] = (bf16)f.x; v[1] = (bf16)f.y; v[2] = (bf16)f.z; v[3] = (bf16)f.w;
    ((bf16x4*)dst)[i] = v;
  }
}

// ---------------- grouped GEMM (round-2 structure, verified 0 bank conflicts) ----------------
// 128^2 tile, BK=64, 256 threads (2x2 waves of 64x64), global_load_lds width16,
// LDS [128][64] linear, both-sides XOR swizzle: phys chunk16 = logical ^ (row&7).
// Block ordering: FFN1 bx-fast (consecutive blocks share the W panel);
// FFN2 by-fast (8 consecutive blocks share one h row-panel -> XCD-local, kills
// the 2-3x h re-fetch from HBM seen in round 2). Both XCD-chunk swizzled (m204).
template<int KDIM, int NCOLS, bool FFN1>
__global__ __launch_bounds__(256) void moe_gemm_kernel(
    const bf16* __restrict__ Asrc, const bf16* __restrict__ Wsrc,
    const float* __restrict__ bias,
    const int* __restrict__ assign_tok, const float* __restrict__ slot_coef,
    const int* __restrict__ po,
    bf16* __restrict__ hout, float* __restrict__ out,
    int chunk_base, int gx)
{
  __shared__ bf16 As[BM][BK];
  __shared__ bf16 Bs[BN][BK];
  __shared__ int toks[BM];

  // bijective XCD chunk swizzle (m204): consecutive wg land on one XCD
  const int nwg = gridDim.x;
  const int lin = blockIdx.x;
  const int q = nwg >> 3, r = nwg & 7;
  const int xcd = lin & 7, idx = lin >> 3;
  const int wg = (xcd < r ? xcd * (q + 1) : r * (q + 1) + (xcd - r) * q) + idx;
  int bx, by;
  if constexpr (FFN1) { bx = wg % gx; by = wg / gx; }       // W-panel-local
  else               { by = wg % (NCOLS / BN); bx = wg / (NCOLS / BN); }  // h-panel-local

  const int po8 = po[NE];
  const int row0 = chunk_base + bx * BM;
  if (row0 >= po8) return;
  int e = 0;
  while (row0 >= po[e + 1]) ++e;
  const int bn0 = by * BN;
  const bf16* We = Wsrc + (size_t)e * ((size_t)HH * DD);
  const int tid = threadIdx.x, lane = tid & 63, wave = tid >> 6;
  if (tid < BM) toks[tid] = assign_tok[row0 + tid];
  __syncthreads();

  // staging: wave handles chunks [wave*4, wave*4+4); chunk c covers rows
  // c*8..c*8+7; lane -> (row = c*8 + lane/8, src col8 = (lane&7) ^ (lane/8))
  const int rin = lane >> 3;
  const int c8s = ((lane & 7) ^ rin) * 8;
  const bf16* asrc[4];
  const bf16* bsrc[4];
  #pragma unroll
  for (int i = 0; i < 4; ++i) {
    const int c = wave * 4 + i;
    const int row = c * 8 + rin;
    int ar;
    if constexpr (FFN1) {
      const int s = toks[row];
      ar = s < 0 ? 0 : s;
    } else {
      ar = row0 - chunk_base + row;
    }
    asrc[i] = Asrc + (size_t)ar * KDIM + c8s;
    bsrc[i] = We + (size_t)(bn0 + row) * KDIM + c8s;
  }

  const int la = lane & 15, hi = lane >> 4;
  const int wm = (wave >> 1) * 64, wn = (wave & 1) * 64;
  f32x4 acc[4][4];
  #pragma unroll
  for (int m = 0; m < 4; ++m)
    #pragma unroll
    for (int n = 0; n < 4; ++n) acc[m][n] = {0.f, 0.f, 0.f, 0.f};

  for (int k0 = 0; k0 < KDIM; k0 += BK) {
    #pragma unroll
    for (int i = 0; i < 4; ++i) gload16(asrc[i] + k0, &As[(wave * 4 + i) * 8][0]);
    #pragma unroll
    for (int i = 0; i < 4; ++i) gload16(bsrc[i] + k0, &Bs[(wave * 4 + i) * 8][0]);
    __syncthreads();   // compiler drains vmcnt before barrier
    #pragma unroll
    for (int ks = 0; ks < 2; ++ks) {
      bf16x8 af[4], bff[4];
      #pragma unroll
      for (int m = 0; m < 4; ++m) {
        const int row = wm + m * 16 + la;
        const int c8 = (ks * 4 + hi) ^ (row & 7);
        af[m] = *(const bf16x8*)(&As[row][c8 * 8]);
      }
      #pragma unroll
      for (int n = 0; n < 4; ++n) {
        const int row = wn + n * 16 + la;
        const int c8 = (ks * 4 + hi) ^ (row & 7);
        bff[n] = *(const bf16x8*)(&Bs[row][c8 * 8]);
      }
      #pragma unroll
      for (int m = 0; m < 4; ++m)
        #pragma unroll
        for (int n = 0; n < 4; ++n)
          acc[m][n] = __builtin_amdgcn_mfma_f32_16x16x32_bf16(af[m], bff[n], acc[m][n], 0, 0, 0);
    }
    __syncthreads();
  }

  if constexpr (FFN1) {
    const int hrow0 = row0 - chunk_base;
    #pragma unroll
    for (int n = 0; n < 4; ++n) {
      const int col = bn0 + wn + n * 16 + la;
      const float bb = bias[e * NCOLS + col];
      #pragma unroll
      for (int m = 0; m < 4; ++m) {
        const int rbase = wm + m * 16 + hi * 4;
        #pragma unroll
        for (int rr = 0; rr < 4; ++rr) {
          float v = acc[m][n][rr] + bb;
          v = v > 0.f ? v : 0.f;
          hout[(size_t)(hrow0 + rbase + rr) * HH + col] = (bf16)v;
        }
      }
    }
  } else {
    #pragma unroll
    for (int n = 0; n < 4; ++n) {
      const int col = bn0 + wn + n * 16 + la;
      const float bb = bias[e * NCOLS + col];
      #pragma unroll
      for (int m = 0; m < 4; ++m) {
        const int rbase = wm + m * 16 + hi * 4;
        #pragma unroll
        for (int rr = 0; rr < 4; ++rr) {
          const int trow = rbase + rr;
          const int tok = toks[trow];
          if (tok >= 0) {
            const float c = slot_coef[row0 + trow];
            atomicAdd(out + (size_t)tok * DD + col, c * (acc[m][n][rr] + bb));
          }
        }
      }
    }
  }
}

extern "C" void kernel_launch(void* const* d_in, const int* in_sizes, int n_in,
                              void* d_out, int out_size, void* d_ws, size_t ws_size,
                              hipStream_t stream) {
  const float* x      = (const float*)d_in[0];
  const float* noise  = (const float*)d_in[1];
  const float* gate_w = (const float*)d_in[2];
  const float* gate_b = (const float*)d_in[3];
  const float* var_w  = (const float*)d_in[4];
  const float* var_b  = (const float*)d_in[5];
  const float* w1     = (const float*)d_in[6];
  const float* b1     = (const float*)d_in[7];
  const float* w2     = (const float*)d_in[8];
  const float* b2     = (const float*)d_in[9];
  float* out = (float*)d_out;
  (void)in_sizes; (void)n_in; (void)out_size;

  char* ws = (char*)d_ws;
  size_t off = 0;
  auto alloc = [&](size_t bytes) {
    off = (off + 255) & ~(size_t)255;
    size_t o = off;
    off += bytes;
    return o;
  };
  bf16*  xb         = (bf16*)(ws + alloc((size_t)NTOK * DD * 2));
  float* coef2      = (float*)(ws + alloc((size_t)NTOK * 2 * 4));
  int*   t2e        = (int*)(ws + alloc((size_t)NTOK * 2 * 4));
  int*   counts     = (int*)(ws + alloc(64));   // counts[8] + cnt2[8]
  int*   cnt2       = counts + 8;
  int*   po         = (int*)(ws + alloc(64));
  int*   assign_tok = (int*)(ws + alloc((size_t)SLOT_CAP * 4));
  float* slot_coef  = (float*)(ws + alloc((size_t)SLOT_CAP * 4));
  bf16*  w1b        = (bf16*)(ws + alloc((size_t)NE * HH * DD * 2));  // 64 MB
  bf16*  w2b        = (bf16*)(ws + alloc((size_t)NE * DD * HH * 2));  // 64 MB
  off = (off + 255) & ~(size_t)255;
  const size_t h_avail = ws_size > off ? ws_size - off : 0;
  int chunk_rows = (int)(h_avail / ((size_t)HH * 2));
  chunk_rows = (chunk_rows / BM) * BM;
  if (chunk_rows < BM) chunk_rows = BM;
  if (chunk_rows > SLOT_CAP) chunk_rows = SLOT_CAP;
  bf16* hbuf = (bf16*)(ws + off);

  hipMemsetAsync(counts, 0, 64, stream);
  hipMemsetAsync(assign_tok, 0xFF, (size_t)SLOT_CAP * 4, stream);  // -1
  hipMemsetAsync(out, 0, (size_t)NTOK * DD * 4, stream);

  moe_gate_kernel<<<NTOK, 64, 0, stream>>>(x, noise, gate_w, gate_b, var_w, var_b,
                                           coef2, t2e, counts, xb);
  moe_offsets_kernel<<<1, 64, 0, stream>>>(counts, po);
  moe_scatter_kernel<<<NTOK / 256, 256, 0, stream>>>(t2e, coef2, po, cnt2,
                                                     assign_tok, slot_coef);
  cvt_bf16_kernel<<<2048, 256, 0, stream>>>(w1, w1b, NE * HH * DD / 4);
  cvt_bf16_kernel<<<2048, 256, 0, stream>>>(w2, w2b, NE * DD * HH / 4);

  const int rounds = (SLOT_CAP + chunk_rows - 1) / chunk_rows;
  for (int r = 0; r < rounds; ++r) {
    const int cb = r * chunk_rows;
    const int rows_here = (cb + chunk_rows <= SLOT_CAP) ? chunk_rows : (SLOT_CAP - cb);
    const int gx = rows_here / BM;
    moe_gemm_kernel<DD, HH, true><<<gx * (HH / BN), 256, 0, stream>>>(
        xb, w1b, b1, assign_tok, slot_coef, po, hbuf, nullptr, cb, gx);
    moe_gemm_kernel<HH, DD, false><<<gx * (DD / BN), 256, 0, stream>>>(
        hbuf, w2b, b2, assign_tok, slot_coef, po, nullptr, out, cb, gx);
  }
}

// Round 8
// 952.954 us; speedup vs baseline: 1.1178x; 1.0039x over previous
//
#include <hip/hip_runtime.h>
#include <hip/hip_bf16.h>
#include <math.h>

#define NTOK 8192     // B*T
#define DD   1024
#define HH   4096
#define NE   8
#define BM 128
#define BN 128
#define BK 64
#define SLOT_CAP (2 * NTOK + NE * BM)   // 17408

typedef __bf16 bf16;
typedef __bf16 bf16x8 __attribute__((ext_vector_type(8)));
typedef __bf16 bf16x4 __attribute__((ext_vector_type(4)));
typedef float  f32x4  __attribute__((ext_vector_type(4)));

typedef __attribute__((address_space(3))) unsigned char lds_u8;
typedef const __attribute__((address_space(1))) unsigned char g_u8;

__device__ __forceinline__ void gload16(const bf16* g, bf16* l) {
  __builtin_amdgcn_global_load_lds((g_u8*)g, (lds_u8*)l, 16, 0, 0);
}

__device__ __forceinline__ float softplus_f(float v) {
  return fmaxf(v, 0.f) + log1pf(expf(-fabsf(v)));
}

// ---------------- K1: gating (1 wave per token) + x->bf16 fold ----------------
__global__ __launch_bounds__(64) void moe_gate_kernel(
    const float* __restrict__ x, const float* __restrict__ noise,
    const float* __restrict__ gate_w, const float* __restrict__ gate_b,
    const float* __restrict__ var_w,  const float* __restrict__ var_b,
    float* __restrict__ coef2, int* __restrict__ t2e, int* __restrict__ counts,
    bf16* __restrict__ xb)
{
  const int t = blockIdx.x;
  const int lane = threadIdx.x;
  const float* xt = x + (size_t)t * DD;
  bf16* xbt = xb + (size_t)t * DD;
  float pg[NE], pv[NE];
  #pragma unroll
  for (int e = 0; e < NE; ++e) { pg[e] = 0.f; pv[e] = 0.f; }
  #pragma unroll 4
  for (int i = 0; i < DD / 64; ++i) {
    const int d = lane + i * 64;
    const float xv = xt[d];
    xbt[d] = (bf16)xv;                    // folded x->bf16 conversion
    #pragma unroll
    for (int e = 0; e < NE; ++e) {
      pg[e] = fmaf(xv, gate_w[e * DD + d], pg[e]);
      pv[e] = fmaf(xv, var_w[e * DD + d], pv[e]);
    }
  }
  #pragma unroll
  for (int e = 0; e < NE; ++e) {
    #pragma unroll
    for (int off = 32; off; off >>= 1) {
      pg[e] += __shfl_xor(pg[e], off);
      pv[e] += __shfl_xor(pv[e], off);
    }
  }
  if (lane == 0) {
    float noisy[NE];
    #pragma unroll
    for (int e = 0; e < NE; ++e) {
      const float lg = pg[e] + gate_b[e];
      const float sd = softplus_f(pv[e] + var_b[e]);
      noisy[e] = lg + noise[t * NE + e] * sd;
    }
    int i1 = 0; float n1 = noisy[0];
    #pragma unroll
    for (int e = 1; e < NE; ++e) if (noisy[e] > n1) { n1 = noisy[e]; i1 = e; }
    int i2 = -1; float n2 = -3.0e38f;
    #pragma unroll
    for (int e = 0; e < NE; ++e) if (e != i1 && noisy[e] > n2) { n2 = noisy[e]; i2 = e; }
    const float e2 = expf(n2 - n1);
    const float den = 1.f + e2;
    coef2[t * 2 + 0] = 1.f / den;
    coef2[t * 2 + 1] = e2 / den;
    t2e[t * 2 + 0] = i1;
    t2e[t * 2 + 1] = i2;
    atomicAdd(&counts[i1], 1);
    atomicAdd(&counts[i2], 1);
  }
}

// ---------------- K2: padded segment offsets (pad to BM=128) ----------------
__global__ void moe_offsets_kernel(const int* __restrict__ counts, int* __restrict__ po) {
  if (threadIdx.x == 0) {
    int acc = 0;
    po[0] = 0;
    for (int e = 0; e < NE; ++e) {
      acc += ((counts[e] + BM - 1) / BM) * BM;
      po[e + 1] = acc;
    }
  }
}

// ---------------- K3: scatter tokens into padded slots ----------------
__global__ __launch_bounds__(256) void moe_scatter_kernel(
    const int* __restrict__ t2e, const float* __restrict__ coef2,
    const int* __restrict__ po, int* __restrict__ cnt2,
    int* __restrict__ assign_tok, float* __restrict__ slot_coef)
{
  const int t = blockIdx.x * 256 + threadIdx.x;
  if (t >= NTOK) return;
  #pragma unroll
  for (int k = 0; k < 2; ++k) {
    const int e = t2e[t * 2 + k];
    const int pos = atomicAdd(&cnt2[e], 1);
    const int slot = po[e] + pos;
    assign_tok[slot] = t;
    slot_coef[slot] = coef2[t * 2 + k];
  }
}

// ---------------- K4: dual f32 -> bf16 converter (grid-stride over float4) ----------------
__global__ __launch_bounds__(256) void cvt2_bf16_kernel(
    const float* __restrict__ s1, bf16* __restrict__ d1, int n41,
    const float* __restrict__ s2, bf16* __restrict__ d2, int n42)
{
  for (int i = blockIdx.x * 256 + threadIdx.x; i < n41 + n42; i += gridDim.x * 256) {
    const float* s = (i < n41) ? s1 : s2;
    bf16* d = (i < n41) ? d1 : d2;
    const int j = (i < n41) ? i : i - n41;
    const float4 f = ((const float4*)s)[j];
    bf16x4 v;
    v[0] = (bf16)f.x; v[1] = (bf16)f.y; v[2] = (bf16)f.z; v[3] = (bf16)f.w;
    ((bf16x4*)d)[j] = v;
  }
}

#define VMCNT8 asm volatile("s_waitcnt vmcnt(8)" ::: "memory")
#define VMCNT0 asm volatile("s_waitcnt vmcnt(0)" ::: "memory")

// ---------------- grouped GEMM: 128^2 tile, BK=64, DOUBLE-buffered LDS ----------------
// R7 base (verified: 0 bank conflicts, XOR chunk swizzle both sides, by-fast
// ordering for FFN2) + the T3/T4 counted-vmcnt pipeline:
//   loop: stage(next -> nb); vmcnt(8) [retires PREVIOUS tile's 8 loads only,
//   prefetch stays in flight]; s_barrier; ds_read(b)+MFMA; s_barrier.
// Raw s_barrier (no auto vmcnt-0 drain). Per-wave stage = exactly 8 gload16.
template<int KDIM, int NCOLS, bool FFN1>
__global__ __launch_bounds__(256) void moe_gemm_kernel(
    const bf16* __restrict__ Asrc, const bf16* __restrict__ Wsrc,
    const float* __restrict__ bias,
    const int* __restrict__ assign_tok, const float* __restrict__ slot_coef,
    const int* __restrict__ po,
    bf16* __restrict__ hout, float* __restrict__ out,
    int chunk_base, int gx)
{
  constexpr int NK = KDIM / BK;
  __shared__ bf16 As[2][BM][BK];   // 32 KB
  __shared__ bf16 Bs[2][BN][BK];   // 32 KB
  __shared__ int toks[BM];

  // bijective XCD chunk swizzle (m204): consecutive wg land on one XCD
  const int nwg = gridDim.x;
  const int lin = blockIdx.x;
  const int q = nwg >> 3, r = nwg & 7;
  const int xcd = lin & 7, idx = lin >> 3;
  const int wg = (xcd < r ? xcd * (q + 1) : r * (q + 1) + (xcd - r) * q) + idx;
  int bx, by;
  if constexpr (FFN1) { bx = wg % gx; by = wg / gx; }       // W-panel-local
  else               { by = wg % (NCOLS / BN); bx = wg / (NCOLS / BN); }  // h-panel-local

  const int po8 = po[NE];
  const int row0 = chunk_base + bx * BM;
  if (row0 >= po8) return;
  int e = 0;
  while (row0 >= po[e + 1]) ++e;
  const int bn0 = by * BN;
  const bf16* We = Wsrc + (size_t)e * ((size_t)HH * DD);
  const int tid = threadIdx.x, lane = tid & 63, wave = tid >> 6;
  if (tid < BM) toks[tid] = assign_tok[row0 + tid];
  __syncthreads();

  // staging: wave handles chunks [wave*4, wave*4+4); chunk c covers rows
  // c*8..c*8+7; lane -> (row = c*8 + lane/8, src col8 = (lane&7) ^ (lane/8))
  const int rin = lane >> 3;
  const int c8s = ((lane & 7) ^ rin) * 8;
  const bf16* asrc[4];
  const bf16* bsrc[4];
  #pragma unroll
  for (int i = 0; i < 4; ++i) {
    const int c = wave * 4 + i;
    const int row = c * 8 + rin;
    int ar;
    if constexpr (FFN1) {
      const int s = toks[row];
      ar = s < 0 ? 0 : s;
    } else {
      ar = row0 - chunk_base + row;
    }
    asrc[i] = Asrc + (size_t)ar * KDIM + c8s;
    bsrc[i] = We + (size_t)(bn0 + row) * KDIM + c8s;
  }

  // exactly 8 global_load_lds per call (vmcnt accounting depends on this)
  auto stage = [&](int sel, int kt) {
    const int k0 = kt * BK;
    #pragma unroll
    for (int i = 0; i < 4; ++i) gload16(asrc[i] + k0, &As[sel][(wave * 4 + i) * 8][0]);
    #pragma unroll
    for (int i = 0; i < 4; ++i) gload16(bsrc[i] + k0, &Bs[sel][(wave * 4 + i) * 8][0]);
  };

  const int la = lane & 15, hi = lane >> 4;
  const int wm = (wave >> 1) * 64, wn = (wave & 1) * 64;
  f32x4 acc[4][4];
  #pragma unroll
  for (int m = 0; m < 4; ++m)
    #pragma unroll
    for (int n = 0; n < 4; ++n) acc[m][n] = {0.f, 0.f, 0.f, 0.f};

  stage(0, 0);   // prologue

  for (int kt = 0; kt < NK; ++kt) {
    const int b = kt & 1;
    if (kt + 1 < NK) {
      stage(b ^ 1, kt + 1);   // prefetch next tile into other buffer
      VMCNT8;                 // retire ONLY previous tile's 8 loads
    } else {
      VMCNT0;                 // final tile: full drain
    }
    __builtin_amdgcn_s_barrier();   // publish buf b across waves

    #pragma unroll
    for (int ks = 0; ks < 2; ++ks) {
      bf16x8 af[4], bff[4];
      #pragma unroll
      for (int m = 0; m < 4; ++m) {
        const int row = wm + m * 16 + la;
        const int c8 = (ks * 4 + hi) ^ (row & 7);
        af[m] = *(const bf16x8*)(&As[b][row][c8 * 8]);
      }
      #pragma unroll
      for (int n = 0; n < 4; ++n) {
        const int row = wn + n * 16 + la;
        const int c8 = (ks * 4 + hi) ^ (row & 7);
        bff[n] = *(const bf16x8*)(&Bs[b][row][c8 * 8]);
      }
      #pragma unroll
      for (int m = 0; m < 4; ++m)
        #pragma unroll
        for (int n = 0; n < 4; ++n)
          acc[m][n] = __builtin_amdgcn_mfma_f32_16x16x32_bf16(af[m], bff[n], acc[m][n], 0, 0, 0);
    }
    __builtin_amdgcn_s_barrier();   // all reads of buf b done -> b reusable
  }

  if constexpr (FFN1) {
    const int hrow0 = row0 - chunk_base;
    #pragma unroll
    for (int n = 0; n < 4; ++n) {
      const int col = bn0 + wn + n * 16 + la;
      const float bb = bias[e * NCOLS + col];
      #pragma unroll
      for (int m = 0; m < 4; ++m) {
        const int rbase = wm + m * 16 + hi * 4;
        #pragma unroll
        for (int rr = 0; rr < 4; ++rr) {
          float v = acc[m][n][rr] + bb;
          v = v > 0.f ? v : 0.f;
          hout[(size_t)(hrow0 + rbase + rr) * HH + col] = (bf16)v;
        }
      }
    }
  } else {
    #pragma unroll
    for (int n = 0; n < 4; ++n) {
      const int col = bn0 + wn + n * 16 + la;
      const float bb = bias[e * NCOLS + col];
      #pragma unroll
      for (int m = 0; m < 4; ++m) {
        const int rbase = wm + m * 16 + hi * 4;
        #pragma unroll
        for (int rr = 0; rr < 4; ++rr) {
          const int trow = rbase + rr;
          const int tok = toks[trow];
          if (tok >= 0) {
            const float c = slot_coef[row0 + trow];
            atomicAdd(out + (size_t)tok * DD + col, c * (acc[m][n][rr] + bb));
          }
        }
      }
    }
  }
}

extern "C" void kernel_launch(void* const* d_in, const int* in_sizes, int n_in,
                              void* d_out, int out_size, void* d_ws, size_t ws_size,
                              hipStream_t stream) {
  const float* x      = (const float*)d_in[0];
  const float* noise  = (const float*)d_in[1];
  const float* gate_w = (const float*)d_in[2];
  const float* gate_b = (const float*)d_in[3];
  const float* var_w  = (const float*)d_in[4];
  const float* var_b  = (const float*)d_in[5];
  const float* w1     = (const float*)d_in[6];
  const float* b1     = (const float*)d_in[7];
  const float* w2     = (const float*)d_in[8];
  const float* b2     = (const float*)d_in[9];
  float* out = (float*)d_out;
  (void)in_sizes; (void)n_in; (void)out_size;

  char* ws = (char*)d_ws;
  size_t off = 0;
  auto alloc = [&](size_t bytes) {
    off = (off + 255) & ~(size_t)255;
    size_t o = off;
    off += bytes;
    return o;
  };
  bf16*  xb         = (bf16*)(ws + alloc((size_t)NTOK * DD * 2));
  float* coef2      = (float*)(ws + alloc((size_t)NTOK * 2 * 4));
  int*   t2e        = (int*)(ws + alloc((size_t)NTOK * 2 * 4));
  int*   counts     = (int*)(ws + alloc(64));   // counts[8] + cnt2[8]
  int*   cnt2       = counts + 8;
  int*   po         = (int*)(ws + alloc(64));
  int*   assign_tok = (int*)(ws + alloc((size_t)SLOT_CAP * 4));
  float* slot_coef  = (float*)(ws + alloc((size_t)SLOT_CAP * 4));
  bf16*  w1b        = (bf16*)(ws + alloc((size_t)NE * HH * DD * 2));  // 64 MB
  bf16*  w2b        = (bf16*)(ws + alloc((size_t)NE * DD * HH * 2));  // 64 MB
  off = (off + 255) & ~(size_t)255;
  const size_t h_avail = ws_size > off ? ws_size - off : 0;
  int chunk_rows = (int)(h_avail / ((size_t)HH * 2));
  chunk_rows = (chunk_rows / BM) * BM;
  if (chunk_rows < BM) chunk_rows = BM;
  if (chunk_rows > SLOT_CAP) chunk_rows = SLOT_CAP;
  bf16* hbuf = (bf16*)(ws + off);

  hipMemsetAsync(counts, 0, 64, stream);
  hipMemsetAsync(assign_tok, 0xFF, (size_t)SLOT_CAP * 4, stream);  // -1
  hipMemsetAsync(out, 0, (size_t)NTOK * DD * 4, stream);

  moe_gate_kernel<<<NTOK, 64, 0, stream>>>(x, noise, gate_w, gate_b, var_w, var_b,
                                           coef2, t2e, counts, xb);
  moe_offsets_kernel<<<1, 64, 0, stream>>>(counts, po);
  moe_scatter_kernel<<<NTOK / 256, 256, 0, stream>>>(t2e, coef2, po, cnt2,
                                                     assign_tok, slot_coef);
  cvt2_bf16_kernel<<<2048, 256, 0, stream>>>(w1, w1b, NE * HH * DD / 4,
                                             w2, w2b, NE * DD * HH / 4);

  const int rounds = (SLOT_CAP + chunk_rows - 1) / chunk_rows;
  for (int r = 0; r < rounds; ++r) {
    const int cb = r * chunk_rows;
    const int rows_here = (cb + chunk_rows <= SLOT_CAP) ? chunk_rows : (SLOT_CAP - cb);
    const int gx = rows_here / BM;
    moe_gemm_kernel<DD, HH, true><<<gx * (HH / BN), 256, 0, stream>>>(
        xb, w1b, b1, assign_tok, slot_coef, po, hbuf, nullptr, cb, gx);
    moe_gemm_kernel<HH, DD, false><<<gx * (DD / BN), 256, 0, stream>>>(
        hbuf, w2b, b2, assign_tok, slot_coef, po, nullptr, out, cb, gx);
  }
}

// Round 9
// 943.238 us; speedup vs baseline: 1.1293x; 1.0103x over previous
//
#include <hip/hip_runtime.h>
#include <hip/hip_bf16.h>
#include <math.h>

#define NTOK 8192     // B*T
#define DD   1024
#define HH   4096
#define NE   8
#define BM 128
#define BN 128
#define BK 64
#define SLOT_CAP (2 * NTOK + NE * BM)   // 17408

typedef __bf16 bf16;
typedef __bf16 bf16x8 __attribute__((ext_vector_type(8)));
typedef __bf16 bf16x4 __attribute__((ext_vector_type(4)));
typedef float  f32x4  __attribute__((ext_vector_type(4)));

typedef __attribute__((address_space(3))) unsigned char lds_u8;
typedef const __attribute__((address_space(1))) unsigned char g_u8;

__device__ __forceinline__ void gload16(const bf16* g, bf16* l) {
  __builtin_amdgcn_global_load_lds((g_u8*)g, (lds_u8*)l, 16, 0, 0);
}

__device__ __forceinline__ float softplus_f(float v) {
  return fmaxf(v, 0.f) + log1pf(expf(-fabsf(v)));
}

// ---------------- K1: gating (1 wave per token) + x->bf16 fold ----------------
__global__ __launch_bounds__(64) void moe_gate_kernel(
    const float* __restrict__ x, const float* __restrict__ noise,
    const float* __restrict__ gate_w, const float* __restrict__ gate_b,
    const float* __restrict__ var_w,  const float* __restrict__ var_b,
    float* __restrict__ coef2, int* __restrict__ t2e, int* __restrict__ counts,
    bf16* __restrict__ xb)
{
  const int t = blockIdx.x;
  const int lane = threadIdx.x;
  const float* xt = x + (size_t)t * DD;
  bf16* xbt = xb + (size_t)t * DD;
  float pg[NE], pv[NE];
  #pragma unroll
  for (int e = 0; e < NE; ++e) { pg[e] = 0.f; pv[e] = 0.f; }
  #pragma unroll 4
  for (int i = 0; i < DD / 64; ++i) {
    const int d = lane + i * 64;
    const float xv = xt[d];
    xbt[d] = (bf16)xv;                    // folded x->bf16 conversion
    #pragma unroll
    for (int e = 0; e < NE; ++e) {
      pg[e] = fmaf(xv, gate_w[e * DD + d], pg[e]);
      pv[e] = fmaf(xv, var_w[e * DD + d], pv[e]);
    }
  }
  #pragma unroll
  for (int e = 0; e < NE; ++e) {
    #pragma unroll
    for (int off = 32; off; off >>= 1) {
      pg[e] += __shfl_xor(pg[e], off);
      pv[e] += __shfl_xor(pv[e], off);
    }
  }
  if (lane == 0) {
    float noisy[NE];
    #pragma unroll
    for (int e = 0; e < NE; ++e) {
      const float lg = pg[e] + gate_b[e];
      const float sd = softplus_f(pv[e] + var_b[e]);
      noisy[e] = lg + noise[t * NE + e] * sd;
    }
    int i1 = 0; float n1 = noisy[0];
    #pragma unroll
    for (int e = 1; e < NE; ++e) if (noisy[e] > n1) { n1 = noisy[e]; i1 = e; }
    int i2 = -1; float n2 = -3.0e38f;
    #pragma unroll
    for (int e = 0; e < NE; ++e) if (e != i1 && noisy[e] > n2) { n2 = noisy[e]; i2 = e; }
    const float e2 = expf(n2 - n1);
    const float den = 1.f + e2;
    coef2[t * 2 + 0] = 1.f / den;
    coef2[t * 2 + 1] = e2 / den;
    t2e[t * 2 + 0] = i1;
    t2e[t * 2 + 1] = i2;
    atomicAdd(&counts[i1], 1);
    atomicAdd(&counts[i2], 1);
  }
}

// ---------------- K2: padded segment offsets (pad to BM=128) ----------------
__global__ void moe_offsets_kernel(const int* __restrict__ counts, int* __restrict__ po) {
  if (threadIdx.x == 0) {
    int acc = 0;
    po[0] = 0;
    for (int e = 0; e < NE; ++e) {
      acc += ((counts[e] + BM - 1) / BM) * BM;
      po[e + 1] = acc;
    }
  }
}

// ---------------- K3: scatter tokens into padded slots ----------------
__global__ __launch_bounds__(256) void moe_scatter_kernel(
    const int* __restrict__ t2e, const float* __restrict__ coef2,
    const int* __restrict__ po, int* __restrict__ cnt2,
    int* __restrict__ assign_tok, float* __restrict__ slot_coef)
{
  const int t = blockIdx.x * 256 + threadIdx.x;
  if (t >= NTOK) return;
  #pragma unroll
  for (int k = 0; k < 2; ++k) {
    const int e = t2e[t * 2 + k];
    const int pos = atomicAdd(&cnt2[e], 1);
    const int slot = po[e] + pos;
    assign_tok[slot] = t;
    slot_coef[slot] = coef2[t * 2 + k];
  }
}

// ---------------- K4: dual f32 -> bf16 converter (grid-stride over float4) ----------------
__global__ __launch_bounds__(256) void cvt2_bf16_kernel(
    const float* __restrict__ s1, bf16* __restrict__ d1, int n41,
    const float* __restrict__ s2, bf16* __restrict__ d2, int n42)
{
  for (int i = blockIdx.x * 256 + threadIdx.x; i < n41 + n42; i += gridDim.x * 256) {
    const float* s = (i < n41) ? s1 : s2;
    bf16* d = (i < n41) ? d1 : d2;
    const int j = (i < n41) ? i : i - n41;
    const float4 f = ((const float4*)s)[j];
    bf16x4 v;
    v[0] = (bf16)f.x; v[1] = (bf16)f.y; v[2] = (bf16)f.z; v[3] = (bf16)f.w;
    ((bf16x4*)d)[j] = v;
  }
}

// ---------------- grouped GEMM (R7 body, verified 0 conflicts) + STRIPE ordering ----------------
// 128^2 tile, BK=64, 256 threads, global_load_lds width16, LDS [128][64] linear,
// both-sides XOR swizzle: phys chunk16 = logical ^ (row&7).
// NEW: supertile (stripe) block order — wg = stripe*(gx*SY) + bx*SY + sy.
//   SY consecutive blocks share the A-panel (stays L2-hot, staged SY times from
//   L2); a stripe's SY W-panels (ffn1 2 MB, ffn2 4 MB) stay L2-resident across
//   all bx of the stripe. Kills the A x32 (ffn1) / W x gx (ffn2) L3 re-streams
//   diagnosed in R8. XCD chunking (m204) keeps stripes XCD-local.
template<int KDIM, int NCOLS, int SY, bool FFN1>
__global__ __launch_bounds__(256) void moe_gemm_kernel(
    const bf16* __restrict__ Asrc, const bf16* __restrict__ Wsrc,
    const float* __restrict__ bias,
    const int* __restrict__ assign_tok, const float* __restrict__ slot_coef,
    const int* __restrict__ po,
    bf16* __restrict__ hout, float* __restrict__ out,
    int chunk_base, int gx)
{
  __shared__ bf16 As[BM][BK];
  __shared__ bf16 Bs[BN][BK];
  __shared__ int toks[BM];

  // bijective XCD chunk swizzle (m204): consecutive wg land on one XCD
  const int nwg = gridDim.x;
  const int lin = blockIdx.x;
  const int q = nwg >> 3, r = nwg & 7;
  const int xcd = lin & 7, idx = lin >> 3;
  const int wg = (xcd < r ? xcd * (q + 1) : r * (q + 1) + (xcd - r) * q) + idx;

  // stripe-grouped decode
  const int ss = gx * SY;
  const int stripe = wg / ss;
  const int rem = wg - stripe * ss;
  const int bx = rem / SY;
  const int by = stripe * SY + (rem - bx * SY);

  const int po8 = po[NE];
  const int row0 = chunk_base + bx * BM;
  if (row0 >= po8) return;
  int e = 0;
  while (row0 >= po[e + 1]) ++e;
  const int bn0 = by * BN;
  const bf16* We = Wsrc + (size_t)e * ((size_t)HH * DD);
  const int tid = threadIdx.x, lane = tid & 63, wave = tid >> 6;
  if (tid < BM) toks[tid] = assign_tok[row0 + tid];
  __syncthreads();

  // staging: wave handles chunks [wave*4, wave*4+4); chunk c covers rows
  // c*8..c*8+7; lane -> (row = c*8 + lane/8, src col8 = (lane&7) ^ (lane/8))
  const int rin = lane >> 3;
  const int c8s = ((lane & 7) ^ rin) * 8;
  const bf16* asrc[4];
  const bf16* bsrc[4];
  #pragma unroll
  for (int i = 0; i < 4; ++i) {
    const int c = wave * 4 + i;
    const int row = c * 8 + rin;
    int ar;
    if constexpr (FFN1) {
      const int s = toks[row];
      ar = s < 0 ? 0 : s;
    } else {
      ar = row0 - chunk_base + row;
    }
    asrc[i] = Asrc + (size_t)ar * KDIM + c8s;
    bsrc[i] = We + (size_t)(bn0 + row) * KDIM + c8s;
  }

  const int la = lane & 15, hi = lane >> 4;
  const int wm = (wave >> 1) * 64, wn = (wave & 1) * 64;
  f32x4 acc[4][4];
  #pragma unroll
  for (int m = 0; m < 4; ++m)
    #pragma unroll
    for (int n = 0; n < 4; ++n) acc[m][n] = {0.f, 0.f, 0.f, 0.f};

  for (int k0 = 0; k0 < KDIM; k0 += BK) {
    #pragma unroll
    for (int i = 0; i < 4; ++i) gload16(asrc[i] + k0, &As[(wave * 4 + i) * 8][0]);
    #pragma unroll
    for (int i = 0; i < 4; ++i) gload16(bsrc[i] + k0, &Bs[(wave * 4 + i) * 8][0]);
    __syncthreads();   // compiler drains vmcnt before barrier
    #pragma unroll
    for (int ks = 0; ks < 2; ++ks) {
      bf16x8 af[4], bff[4];
      #pragma unroll
      for (int m = 0; m < 4; ++m) {
        const int row = wm + m * 16 + la;
        const int c8 = (ks * 4 + hi) ^ (row & 7);
        af[m] = *(const bf16x8*)(&As[row][c8 * 8]);
      }
      #pragma unroll
      for (int n = 0; n < 4; ++n) {
        const int row = wn + n * 16 + la;
        const int c8 = (ks * 4 + hi) ^ (row & 7);
        bff[n] = *(const bf16x8*)(&Bs[row][c8 * 8]);
      }
      #pragma unroll
      for (int m = 0; m < 4; ++m)
        #pragma unroll
        for (int n = 0; n < 4; ++n)
          acc[m][n] = __builtin_amdgcn_mfma_f32_16x16x32_bf16(af[m], bff[n], acc[m][n], 0, 0, 0);
    }
    __syncthreads();
  }

  if constexpr (FFN1) {
    const int hrow0 = row0 - chunk_base;
    #pragma unroll
    for (int n = 0; n < 4; ++n) {
      const int col = bn0 + wn + n * 16 + la;
      const float bb = bias[e * NCOLS + col];
      #pragma unroll
      for (int m = 0; m < 4; ++m) {
        const int rbase = wm + m * 16 + hi * 4;
        #pragma unroll
        for (int rr = 0; rr < 4; ++rr) {
          float v = acc[m][n][rr] + bb;
          v = v > 0.f ? v : 0.f;
          hout[(size_t)(hrow0 + rbase + rr) * HH + col] = (bf16)v;
        }
      }
    }
  } else {
    #pragma unroll
    for (int n = 0; n < 4; ++n) {
      const int col = bn0 + wn + n * 16 + la;
      const float bb = bias[e * NCOLS + col];
      #pragma unroll
      for (int m = 0; m < 4; ++m) {
        const int rbase = wm + m * 16 + hi * 4;
        #pragma unroll
        for (int rr = 0; rr < 4; ++rr) {
          const int trow = rbase + rr;
          const int tok = toks[trow];
          if (tok >= 0) {
            const float c = slot_coef[row0 + trow];
            atomicAdd(out + (size_t)tok * DD + col, c * (acc[m][n][rr] + bb));
          }
        }
      }
    }
  }
}

extern "C" void kernel_launch(void* const* d_in, const int* in_sizes, int n_in,
                              void* d_out, int out_size, void* d_ws, size_t ws_size,
                              hipStream_t stream) {
  const float* x      = (const float*)d_in[0];
  const float* noise  = (const float*)d_in[1];
  const float* gate_w = (const float*)d_in[2];
  const float* gate_b = (const float*)d_in[3];
  const float* var_w  = (const float*)d_in[4];
  const float* var_b  = (const float*)d_in[5];
  const float* w1     = (const float*)d_in[6];
  const float* b1     = (const float*)d_in[7];
  const float* w2     = (const float*)d_in[8];
  const float* b2     = (const float*)d_in[9];
  float* out = (float*)d_out;
  (void)in_sizes; (void)n_in; (void)out_size;

  char* ws = (char*)d_ws;
  size_t off = 0;
  auto alloc = [&](size_t bytes) {
    off = (off + 255) & ~(size_t)255;
    size_t o = off;
    off += bytes;
    return o;
  };
  bf16*  xb         = (bf16*)(ws + alloc((size_t)NTOK * DD * 2));
  float* coef2      = (float*)(ws + alloc((size_t)NTOK * 2 * 4));
  int*   t2e        = (int*)(ws + alloc((size_t)NTOK * 2 * 4));
  int*   counts     = (int*)(ws + alloc(64));   // counts[8] + cnt2[8]
  int*   cnt2       = counts + 8;
  int*   po         = (int*)(ws + alloc(64));
  int*   assign_tok = (int*)(ws + alloc((size_t)SLOT_CAP * 4));
  float* slot_coef  = (float*)(ws + alloc((size_t)SLOT_CAP * 4));
  bf16*  w1b        = (bf16*)(ws + alloc((size_t)NE * HH * DD * 2));  // 64 MB
  bf16*  w2b        = (bf16*)(ws + alloc((size_t)NE * DD * HH * 2));  // 64 MB
  off = (off + 255) & ~(size_t)255;
  const size_t h_avail = ws_size > off ? ws_size - off : 0;
  int chunk_rows = (int)(h_avail / ((size_t)HH * 2));
  chunk_rows = (chunk_rows / BM) * BM;
  if (chunk_rows < BM) chunk_rows = BM;
  if (chunk_rows > SLOT_CAP) chunk_rows = SLOT_CAP;
  bf16* hbuf = (bf16*)(ws + off);

  hipMemsetAsync(counts, 0, 64, stream);
  hipMemsetAsync(assign_tok, 0xFF, (size_t)SLOT_CAP * 4, stream);  // -1
  hipMemsetAsync(out, 0, (size_t)NTOK * DD * 4, stream);

  moe_gate_kernel<<<NTOK, 64, 0, stream>>>(x, noise, gate_w, gate_b, var_w, var_b,
                                           coef2, t2e, counts, xb);
  moe_offsets_kernel<<<1, 64, 0, stream>>>(counts, po);
  moe_scatter_kernel<<<NTOK / 256, 256, 0, stream>>>(t2e, coef2, po, cnt2,
                                                     assign_tok, slot_coef);
  cvt2_bf16_kernel<<<2048, 256, 0, stream>>>(w1, w1b, NE * HH * DD / 4,
                                             w2, w2b, NE * DD * HH / 4);

  const int rounds = (SLOT_CAP + chunk_rows - 1) / chunk_rows;
  for (int r = 0; r < rounds; ++r) {
    const int cb = r * chunk_rows;
    const int rows_here = (cb + chunk_rows <= SLOT_CAP) ? chunk_rows : (SLOT_CAP - cb);
    const int gx = rows_here / BM;
    // SY=8 for ffn1 (stripe W set 2 MB), SY=4 for ffn2 (stripe W set 4 MB)
    moe_gemm_kernel<DD, HH, 8, true><<<gx * (HH / BN), 256, 0, stream>>>(
        xb, w1b, b1, assign_tok, slot_coef, po, hbuf, nullptr, cb, gx);
    moe_gemm_kernel<HH, DD, 4, false><<<gx * (DD / BN), 256, 0, stream>>>(
        hbuf, w2b, b2, assign_tok, slot_coef, po, nullptr, out, cb, gx);
  }
}